// Round 4
// baseline (18342.773 us; speedup 1.0000x reference)
//
#include <hip/hip_runtime.h>

// LSTM classifier, MI355X.
// Decomposition:
//   emb = glove[ids];  x_t = [emb_t, emb_{t-1}]
//   x @ W_ih^T  ==  G1[ids_t] + G2[ids_{t-1}]   with G1 = glove@Wa^T, G2 = glove@Wb^T
// The only serial work is h @ W_hh^T, which is batch-parallel (16 wgs x 16 rows,
// no inter-wg sync; h double-buffered in LDS, one __syncthreads per step).
//
// ws layout (prefix is enough for the fallback path):
//   WhhS  @ 0          819,200 B   [80 tile(ct*4+gb)][10 ks][64 L][8] bf16
//   WihS  @ 819,200  1,556,480 B   [80 tile][19 ks][64 L][8] bf16 (fallback only)
//   biasq @ 2,375,680    5,120 B   [320*4] f32 quad-interleaved (b_ih+b_hh)
//   Wq    @ 2,380,800 1,536,000 B  [2 tab][75 ct][10 ks][64 L][8] bf16 (full only)
//   G     @ 3,916,800 240,000,000B [2][50000][1200] bf16, col' = j*4+gate (full only)
// FULL total = 243,916,800 B. If ws_size is smaller, fall back to computing the
// input GEMM on the fly inside lstm_rec (needs only the 2.38 MB prefix).

typedef __attribute__((ext_vector_type(8))) short s16x8;
typedef __attribute__((ext_vector_type(4))) short s16x4;
typedef __attribute__((ext_vector_type(4))) float f32x4;

#define FULL_WS_BYTES 243916800ull

__device__ __forceinline__ float bf2f(short s) {
  unsigned u = ((unsigned)(unsigned short)s) << 16;
  float f; __builtin_memcpy(&f, &u, 4); return f;
}
__device__ __forceinline__ short f2bf(float f) {
  unsigned u; __builtin_memcpy(&u, &f, 4);
  unsigned r = u + 0x7fffu + ((u >> 16) & 1u);   // RNE
  return (short)(r >> 16);
}
__device__ __forceinline__ f32x4 mfma16(s16x8 a, s16x8 b, f32x4 c) {
  return __builtin_amdgcn_mfma_f32_16x16x32_bf16(a, b, c, 0, 0, 0);
}
__device__ __forceinline__ float sigm(float x) { return 1.f / (1.f + __expf(-x)); }
__device__ __forceinline__ float tanh_(float x) {
  float e = __expf(2.f * x);          // inf-safe: x>>0 -> 1 ; x<<0 -> -1
  return 1.f - 2.f / (e + 1.f);
}

// ---------------- prep: weight fragment swizzles + bias ----------------
__global__ void prep_w(const float* __restrict__ Wih, const float* __restrict__ Whh_in,
                       const float* __restrict__ bih, const float* __restrict__ bhh,
                       short* __restrict__ Wq, short* __restrict__ WhhS,
                       short* __restrict__ WihS, float* __restrict__ biasq, int full) {
  int idx = blockIdx.x * 256 + threadIdx.x;       // 960*256 = 245,760
  if (idx < 96000) {                              // Wq (full path only)
    if (!full) return;
    int tab = idx / 48000; int r = idx % 48000;
    int L = r % 64;
    int colp = (r / 640) * 16 + (L & 15);         // ct*16 + lane-col, in [0,1200)
    int rowW = (colp & 3) * 300 + (colp >> 2);    // gate*300 + j
#pragma unroll
    for (int i = 0; i < 8; ++i) {
      int k = ((r / 64) % 10) * 32 + (L >> 4) * 8 + i;
      float v = (k < 300) ? Wih[(size_t)rowW * 600 + 300 * tab + k] : 0.f;
      Wq[(size_t)idx * 8 + i] = f2bf(v);
    }
  } else if (idx < 147200) {                      // WhhS
    int r = idx - 96000;
    int tIdx = r / 640; int L = r % 64;
    int ct = tIdx >> 2, gb = tIdx & 3;
    int j = ct * 16 + (L & 15);
#pragma unroll
    for (int i = 0; i < 8; ++i) {
      int k = ((r / 64) % 10) * 32 + (L >> 4) * 8 + i;
      float v = (j < 300 && k < 300) ? Whh_in[(size_t)(gb * 300 + j) * 300 + k] : 0.f;
      WhhS[(size_t)r * 8 + i] = f2bf(v);
    }
  } else if (idx < 244480) {                      // WihS (fallback): r=(tile*19+ks)*64+L
    int r = idx - 147200;
    int tile = r / 1216; int L = r % 64;          // 1216 = 19*64
    int ct = tile >> 2, gb = tile & 3;
    int j = ct * 16 + (L & 15);
    int ksg = (r / 64) % 19;
#pragma unroll
    for (int i = 0; i < 8; ++i) {
      int k = ksg * 32 + (L >> 4) * 8 + i;
      float v = (j < 300 && k < 600) ? Wih[(size_t)(gb * 300 + j) * 600 + k] : 0.f;
      WihS[(size_t)r * 8 + i] = f2bf(v);
    }
  } else if (idx < 245760) {                      // biasq
    int r = idx - 244480; int j = r >> 2, gb = r & 3;
    biasq[r] = (j < 300) ? (bih[gb * 300 + j] + bhh[gb * 300 + j]) : 0.f;
  }
}

// ---------------- table GEMM: G[tab][v][col'] = glove @ W^T (f32 A, cvt in reg) ----
__device__ __forceinline__ s16x8 loadA_gl(const float* __restrict__ g, int r, int k0) {
  s16x8 v;
  if (r < 50000) {
    if (k0 + 8 <= 300) {
      const float* p = g + (size_t)r * 300 + k0;
      f32x4 a = *(const f32x4*)p, b = *(const f32x4*)(p + 4);
      v[0] = f2bf(a.x); v[1] = f2bf(a.y); v[2] = f2bf(a.z); v[3] = f2bf(a.w);
      v[4] = f2bf(b.x); v[5] = f2bf(b.y); v[6] = f2bf(b.z); v[7] = f2bf(b.w);
    } else {
#pragma unroll
      for (int i = 0; i < 8; ++i) {
        int k = k0 + i;
        v[i] = (k < 300) ? f2bf(g[(size_t)r * 300 + k]) : (short)0;
      }
    }
  } else {
#pragma unroll
    for (int i = 0; i < 8; ++i) v[i] = 0;
  }
  return v;
}

__global__ __launch_bounds__(256, 2) void tab_gemm(const float* __restrict__ gl,
                                                   const short* __restrict__ Wq,
                                                   short* __restrict__ G) {
  int bid = blockIdx.x;                 // 391*15 blocks
  int nt = bid % 15, mt = bid / 15;
  int tid = threadIdx.x, L = tid & 63, w = tid >> 6;
  int ln = L & 15, kg = L >> 4;
  int v0 = mt * 128;

  f32x4 acc[2][2][5];
#pragma unroll
  for (int a = 0; a < 2; ++a)
#pragma unroll
    for (int b = 0; b < 2; ++b)
#pragma unroll
      for (int c = 0; c < 5; ++c) acc[a][b][c] = (f32x4){0.f, 0.f, 0.f, 0.f};

#pragma unroll
  for (int ks = 0; ks < 10; ++ks) {
    int r0 = v0 + (2 * w) * 16 + ln;
    int k0 = ks * 32 + kg * 8;
    s16x8 A0 = loadA_gl(gl, r0, k0);
    s16x8 A1 = loadA_gl(gl, r0 + 16, k0);
#pragma unroll
    for (int tab = 0; tab < 2; ++tab)
#pragma unroll
      for (int ctl = 0; ctl < 5; ++ctl) {
        const short* bp = Wq + ((((size_t)tab * 75 + nt * 5 + ctl) * 10 + ks) * 64 + L) * 8;
        s16x8 B = *(const s16x8*)bp;
        acc[tab][0][ctl] = mfma16(A0, B, acc[tab][0][ctl]);
        acc[tab][1][ctl] = mfma16(A1, B, acc[tab][1][ctl]);
      }
  }
#pragma unroll
  for (int tab = 0; tab < 2; ++tab)
#pragma unroll
    for (int rtl = 0; rtl < 2; ++rtl)
#pragma unroll
      for (int ctl = 0; ctl < 5; ++ctl)
#pragma unroll
        for (int r = 0; r < 4; ++r) {
          int v = v0 + (2 * w + rtl) * 16 + kg * 4 + r;
          if (v < 50000) {
            int colp = nt * 80 + ctl * 16 + ln;
            G[((size_t)tab * 50000 + v) * 1200 + colp] = f2bf(acc[tab][rtl][ctl][r]);
          }
        }
}

// ---------------- recurrent persistent kernel: 16 wgs x 512 thr ----------------
struct LoopSh { short x[2][16][616]; short h[2][16][328]; };  // 39,424 + 20,992 B
struct TailSh { float pool[16][304]; float l1[16][100]; float l2[16][5]; };
union ShU { LoopSh loop; TailSh tail; };                      // 60,416 B

template <int ONFLY>
__global__ __launch_bounds__(512, 2) void lstm_rec(
    const int* __restrict__ ids, const float* __restrict__ glove,
    const short* __restrict__ G, const short* __restrict__ Whh,
    const short* __restrict__ WihF, const float* __restrict__ biasq,
    const float* __restrict__ W1, const float* __restrict__ b1,
    const float* __restrict__ W2, const float* __restrict__ b2,
    float* __restrict__ out) {
  __shared__ ShU sh;

  const int tid = threadIdx.x;
  const int L = tid & 63, w = tid >> 6;           // 8 waves
  const int ln = L & 15, kg = L >> 4;
  const int b0 = blockIdx.x * 16;
  const int nct = (w < 4) ? 3 : 2;                // 20 col-tiles over 8 waves
  const int cts[3] = {w, w + 8, w + 16};          // per-SIMD balanced (5 tiles/SIMD-pair)

  for (int i = tid; i < (int)(sizeof(LoopSh) / 2); i += 512) ((short*)&sh.loop)[i] = 0;

  int jj[3];
  f32x4 bq[3];
#pragma unroll
  for (int s = 0; s < 3; ++s) {
    jj[s] = cts[s] * 16 + ln;
    if (s < nct) bq[s] = *(const f32x4*)(biasq + 4 * jj[s]);
  }
  float creg[3][4] = {};
  float pool[3][4] = {};
  int id_prev[4] = {};

  __syncthreads();

  for (int t = 0; t < 512; ++t) {
    int id_cur[4];
#pragma unroll
    for (int r = 0; r < 4; ++r)
      id_cur[r] = ids[(size_t)(b0 + kg * 4 + r) * 512 + t];

    if (ONFLY) {
      // stage emb_t -> x[t&1][.][0:300] and x[(t+1)&1][.][300:600]
      int r2 = tid >> 5, cl = tid & 31;
      int idt = (t < 511) ? ids[(size_t)(b0 + r2) * 512 + t] : 0;
#pragma unroll
      for (int q = 0; q < 10; ++q) {
        int c = cl + 32 * q;
        if (c < 300) {
          float v = (t < 511) ? glove[(size_t)idt * 300 + c] : 0.f;  // emb[:,511,:]=0
          short bv = f2bf(v);
          sh.loop.x[t & 1][r2][c] = bv;
          sh.loop.x[(t + 1) & 1][r2][300 + c] = bv;
        }
      }
      __syncthreads();
    }

    // A fragments: h from LDS buffer (t+1)&1
    s16x8 A[10];
#pragma unroll
    for (int ks = 0; ks < 10; ++ks)
      A[ks] = *(const s16x8*)(&sh.loop.h[(t + 1) & 1][ln][ks * 32 + kg * 8]);
    s16x8 AX[ONFLY ? 19 : 1];
    if (ONFLY) {
#pragma unroll
      for (int ks = 0; ks < 19; ++ks)
        AX[ks] = *(const s16x8*)(&sh.loop.x[t & 1][ln][ks * 32 + kg * 8]);
    }

    f32x4 acc[3][4];
#pragma unroll
    for (int s = 0; s < 3; ++s) {
      if (s >= nct) continue;
#pragma unroll
      for (int gb = 0; gb < 4; ++gb) {
        f32x4 a = (f32x4){0.f, 0.f, 0.f, 0.f};
        const short* wb = Whh + (size_t)(cts[s] * 4 + gb) * 10 * 512;
#pragma unroll
        for (int ks = 0; ks < 10; ++ks) {
          s16x8 B = *(const s16x8*)(wb + (ks * 64 + L) * 8);
          a = mfma16(A[ks], B, a);
        }
        if (ONFLY) {
          const short* wx = WihF + (size_t)(cts[s] * 4 + gb) * 19 * 512;
#pragma unroll
          for (int ks = 0; ks < 19; ++ks) {
            s16x8 B = *(const s16x8*)(wx + (ks * 64 + L) * 8);
            a = mfma16(AX[ks], B, a);
          }
        }
        acc[s][gb] = a;
      }
    }

    // epilogue: gather(+full-path G) + bias + activations + c/h update
#pragma unroll
    for (int s = 0; s < 3; ++s) {
      if (s >= nct) continue;
      const int j = jj[s];
      const int jc = (j < 300) ? j : 299;
#pragma unroll
      for (int r = 0; r < 4; ++r) {
        float g1[4] = {0.f, 0.f, 0.f, 0.f}, g2[4] = {0.f, 0.f, 0.f, 0.f};
        if (!ONFLY) {
          if (t != 511) {                       // emb[:,511,:] zeroed in reference
            s16x4 q = *(const s16x4*)(G + (size_t)id_cur[r] * 1200 + 4 * jc);
            g1[0] = bf2f(q.x); g1[1] = bf2f(q.y); g1[2] = bf2f(q.z); g1[3] = bf2f(q.w);
          }
          if (t != 0) {                         // shift zero-padded at t=0
            s16x4 q = *(const s16x4*)(G + ((size_t)50000 + id_prev[r]) * 1200 + 4 * jc);
            g2[0] = bf2f(q.x); g2[1] = bf2f(q.y); g2[2] = bf2f(q.z); g2[3] = bf2f(q.w);
          }
        }
        float pi = acc[s][0][r] + g1[0] + g2[0] + bq[s].x;
        float pf = acc[s][1][r] + g1[1] + g2[1] + bq[s].y;
        float pg = acc[s][2][r] + g1[2] + g2[2] + bq[s].z;
        float po = acc[s][3][r] + g1[3] + g2[3] + bq[s].w;
        float iv = sigm(pi), fv = sigm(pf), gv = tanh_(pg), ov = sigm(po);
        float c = fv * creg[s][r] + iv * gv;
        creg[s][r] = c;
        float h = ov * tanh_(c);
        if (j >= 300) h = 0.f;                  // padded h columns stay zero
        pool[s][r] += h;
        sh.loop.h[t & 1][kg * 4 + r][j] = f2bf(h);
      }
    }
#pragma unroll
    for (int r = 0; r < 4; ++r) id_prev[r] = id_cur[r];
    __syncthreads();
  }

  // ---- tail: pooled mean -> l1 -> l2 -> log_softmax (overlays loop LDS) ----
#pragma unroll
  for (int s = 0; s < 3; ++s) {
    if (s >= nct) continue;
    if (jj[s] < 300) {
#pragma unroll
      for (int r = 0; r < 4; ++r)
        sh.tail.pool[kg * 4 + r][jj[s]] = pool[s][r] * (1.f / 512.f);
    }
  }
  __syncthreads();

  for (int k = 0; k < 4; ++k) {                  // 1600 dots of 300
    int it = tid + 512 * k;
    if (it < 1600) {
      int b = it & 15, o = it >> 4;
      const float* w1r = W1 + (size_t)o * 300;
      float d = b1[o];
      for (int q = 0; q < 75; ++q) {
        f32x4 pv = *(const f32x4*)(&sh.tail.pool[b][q * 4]);
        f32x4 wv = *(const f32x4*)(w1r + q * 4);
        d += pv.x * wv.x + pv.y * wv.y + pv.z * wv.z + pv.w * wv.w;
      }
      sh.tail.l1[b][o] = sigm(d);
    }
  }
  __syncthreads();
  if (tid < 80) {                                // l2: 16 rows x 5 outs
    int b = tid & 15, o = tid >> 4;
    float d = b2[o];
    for (int q = 0; q < 100; ++q) d += sh.tail.l1[b][q] * W2[o * 100 + q];
    sh.tail.l2[b][o] = sigm(d);
  }
  __syncthreads();
  if (tid < 16) {                                // log_softmax over 5 classes
    float x0 = sh.tail.l2[tid][0], x1 = sh.tail.l2[tid][1], x2 = sh.tail.l2[tid][2],
          x3 = sh.tail.l2[tid][3], x4 = sh.tail.l2[tid][4];
    float m = fmaxf(fmaxf(fmaxf(x0, x1), fmaxf(x2, x3)), x4);
    float ssum = __expf(x0 - m) + __expf(x1 - m) + __expf(x2 - m) +
                 __expf(x3 - m) + __expf(x4 - m);
    float ls = __logf(ssum);
    float* po = out + (size_t)(b0 + tid) * 5;
    po[0] = x0 - m - ls; po[1] = x1 - m - ls; po[2] = x2 - m - ls;
    po[3] = x3 - m - ls; po[4] = x4 - m - ls;
  }
}

extern "C" void kernel_launch(void* const* d_in, const int* in_sizes, int n_in,
                              void* d_out, int out_size, void* d_ws, size_t ws_size,
                              hipStream_t stream) {
  const int*   ids   = (const int*)d_in[0];
  // d_in[1] = max_num_of_words (512), hardcoded
  const float* glove = (const float*)d_in[2];
  const float* W_ih  = (const float*)d_in[3];
  const float* W_hh  = (const float*)d_in[4];
  const float* b_ih  = (const float*)d_in[5];
  const float* b_hh  = (const float*)d_in[6];
  const float* W1    = (const float*)d_in[7];
  const float* b1    = (const float*)d_in[8];
  const float* W2    = (const float*)d_in[9];
  const float* b2    = (const float*)d_in[10];
  float* out = (float*)d_out;

  char* ws = (char*)d_ws;
  short* WhhS  = (short*)(ws);                   //   819,200 B
  short* WihS  = (short*)(ws + 819200);          // 1,556,480 B
  float* biasq = (float*)(ws + 2375680);         //     5,120 B
  short* Wq    = (short*)(ws + 2380800);         // 1,536,000 B (full only)
  short* G     = (short*)(ws + 3916800);         // 240,000,000 B (full only)

  const int full = (ws_size >= (size_t)FULL_WS_BYTES) ? 1 : 0;

  prep_w<<<960, 256, 0, stream>>>(W_ih, W_hh, b_ih, b_hh, Wq, WhhS, WihS, biasq, full);
  if (full) {
    tab_gemm<<<5865, 256, 0, stream>>>(glove, Wq, G);
    lstm_rec<0><<<16, 512, 0, stream>>>(ids, glove, G, WhhS, WihS, biasq,
                                        W1, b1, W2, b2, out);
  } else {
    lstm_rec<1><<<16, 512, 0, stream>>>(ids, glove, G, WhhS, WihS, biasq,
                                        W1, b1, W2, b2, out);
  }
}

// Round 5
// 18200.752 us; speedup vs baseline: 1.0078x; 1.0078x over previous
//
#include <hip/hip_runtime.h>

// LSTM classifier, MI355X.
// emb = glove[ids];  x_t = [emb_t, emb_{t-1}]
// x @ W_ih^T == G1[ids_t] + G2[ids_{t-1}]  (G tables precomputed by tab_gemm)
// Serial part: h @ W_hh^T, batch-parallel: 16 wgs x 16 rows, h in LDS.
// R4 fix: epilogue G-gathers were 24 serialized HBM round trips per step
// (MfmaUtil 0.23%, VALUBusy 0.8% -> latency-bound). Now: ids prefetched at
// step start; gathers for step t+1 issued AFTER the B/MFMA phase (so MFMA
// waitcnts never wait on them), held in regs across the barrier, consumed
// next step with zero wait. Epilogue has no global loads.
//
// ws layout:
//   WhhS  @ 0          819,200 B   [80 tile(ct*4+gb)][10 ks][64 L][8] bf16
//   WihS  @ 819,200  1,556,480 B   (fallback only)
//   biasq @ 2,375,680    5,120 B   [320*4] f32 quad-interleaved
//   Wq    @ 2,380,800 1,536,000 B  (full only)
//   G     @ 3,916,800 240,000,000B [2][50000][1200] bf16, col' = j*4+gate
// FULL total = 243,916,800 B; smaller ws -> on-the-fly input GEMM fallback.

typedef __attribute__((ext_vector_type(8))) short s16x8;
typedef __attribute__((ext_vector_type(4))) short s16x4;
typedef __attribute__((ext_vector_type(4))) float f32x4;

#define FULL_WS_BYTES 243916800ull

__device__ __forceinline__ float bf2f(short s) {
  unsigned u = ((unsigned)(unsigned short)s) << 16;
  float f; __builtin_memcpy(&f, &u, 4); return f;
}
__device__ __forceinline__ short f2bf(float f) {
  unsigned u; __builtin_memcpy(&u, &f, 4);
  unsigned r = u + 0x7fffu + ((u >> 16) & 1u);   // RNE
  return (short)(r >> 16);
}
__device__ __forceinline__ f32x4 mfma16(s16x8 a, s16x8 b, f32x4 c) {
  return __builtin_amdgcn_mfma_f32_16x16x32_bf16(a, b, c, 0, 0, 0);
}
__device__ __forceinline__ float sigm(float x) { return 1.f / (1.f + __expf(-x)); }
__device__ __forceinline__ float tanh_(float x) {
  float e = __expf(2.f * x);          // inf-safe
  return 1.f - 2.f / (e + 1.f);
}

// ---------------- prep: weight fragment swizzles + bias ----------------
__global__ void prep_w(const float* __restrict__ Wih, const float* __restrict__ Whh_in,
                       const float* __restrict__ bih, const float* __restrict__ bhh,
                       short* __restrict__ Wq, short* __restrict__ WhhS,
                       short* __restrict__ WihS, float* __restrict__ biasq, int full) {
  int idx = blockIdx.x * 256 + threadIdx.x;       // 960*256 = 245,760
  if (idx < 96000) {                              // Wq (full path only)
    if (!full) return;
    int tab = idx / 48000; int r = idx % 48000;
    int L = r % 64;
    int colp = (r / 640) * 16 + (L & 15);
    int rowW = (colp & 3) * 300 + (colp >> 2);    // gate*300 + j
#pragma unroll
    for (int i = 0; i < 8; ++i) {
      int k = ((r / 64) % 10) * 32 + (L >> 4) * 8 + i;
      float v = (k < 300) ? Wih[(size_t)rowW * 600 + 300 * tab + k] : 0.f;
      Wq[(size_t)idx * 8 + i] = f2bf(v);
    }
  } else if (idx < 147200) {                      // WhhS
    int r = idx - 96000;
    int tIdx = r / 640; int L = r % 64;
    int ct = tIdx >> 2, gb = tIdx & 3;
    int j = ct * 16 + (L & 15);
#pragma unroll
    for (int i = 0; i < 8; ++i) {
      int k = ((r / 64) % 10) * 32 + (L >> 4) * 8 + i;
      float v = (j < 300 && k < 300) ? Whh_in[(size_t)(gb * 300 + j) * 300 + k] : 0.f;
      WhhS[(size_t)r * 8 + i] = f2bf(v);
    }
  } else if (idx < 244480) {                      // WihS (fallback)
    int r = idx - 147200;
    int tile = r / 1216; int L = r % 64;
    int ct = tile >> 2, gb = tile & 3;
    int j = ct * 16 + (L & 15);
    int ksg = (r / 64) % 19;
#pragma unroll
    for (int i = 0; i < 8; ++i) {
      int k = ksg * 32 + (L >> 4) * 8 + i;
      float v = (j < 300 && k < 600) ? Wih[(size_t)(gb * 300 + j) * 600 + k] : 0.f;
      WihS[(size_t)r * 8 + i] = f2bf(v);
    }
  } else if (idx < 245760) {                      // biasq
    int r = idx - 244480; int j = r >> 2, gb = r & 3;
    biasq[r] = (j < 300) ? (bih[gb * 300 + j] + bhh[gb * 300 + j]) : 0.f;
  }
}

// ---------------- table GEMM: G[tab][v][col'] = glove @ W^T ----------------
__device__ __forceinline__ s16x8 loadA_gl(const float* __restrict__ g, int r, int k0) {
  s16x8 v;
  if (r < 50000) {
    if (k0 + 8 <= 300) {
      const float* p = g + (size_t)r * 300 + k0;
      f32x4 a = *(const f32x4*)p, b = *(const f32x4*)(p + 4);
      v[0] = f2bf(a.x); v[1] = f2bf(a.y); v[2] = f2bf(a.z); v[3] = f2bf(a.w);
      v[4] = f2bf(b.x); v[5] = f2bf(b.y); v[6] = f2bf(b.z); v[7] = f2bf(b.w);
    } else {
#pragma unroll
      for (int i = 0; i < 8; ++i) {
        int k = k0 + i;
        v[i] = (k < 300) ? f2bf(g[(size_t)r * 300 + k]) : (short)0;
      }
    }
  } else {
#pragma unroll
    for (int i = 0; i < 8; ++i) v[i] = 0;
  }
  return v;
}

__global__ __launch_bounds__(256, 2) void tab_gemm(const float* __restrict__ gl,
                                                   const short* __restrict__ Wq,
                                                   short* __restrict__ G) {
  int bid = blockIdx.x;                 // 391*15 blocks
  int nt = bid % 15, mt = bid / 15;
  int tid = threadIdx.x, L = tid & 63, w = tid >> 6;
  int ln = L & 15, kg = L >> 4;
  int v0 = mt * 128;

  f32x4 acc[2][2][5];
#pragma unroll
  for (int a = 0; a < 2; ++a)
#pragma unroll
    for (int b = 0; b < 2; ++b)
#pragma unroll
      for (int c = 0; c < 5; ++c) acc[a][b][c] = (f32x4){0.f, 0.f, 0.f, 0.f};

#pragma unroll
  for (int ks = 0; ks < 10; ++ks) {
    int r0 = v0 + (2 * w) * 16 + ln;
    int k0 = ks * 32 + kg * 8;
    s16x8 A0 = loadA_gl(gl, r0, k0);
    s16x8 A1 = loadA_gl(gl, r0 + 16, k0);
#pragma unroll
    for (int tab = 0; tab < 2; ++tab)
#pragma unroll
      for (int ctl = 0; ctl < 5; ++ctl) {
        const short* bp = Wq + ((((size_t)tab * 75 + nt * 5 + ctl) * 10 + ks) * 64 + L) * 8;
        s16x8 B = *(const s16x8*)bp;
        acc[tab][0][ctl] = mfma16(A0, B, acc[tab][0][ctl]);
        acc[tab][1][ctl] = mfma16(A1, B, acc[tab][1][ctl]);
      }
  }
#pragma unroll
  for (int tab = 0; tab < 2; ++tab)
#pragma unroll
    for (int rtl = 0; rtl < 2; ++rtl)
#pragma unroll
      for (int ctl = 0; ctl < 5; ++ctl)
#pragma unroll
        for (int r = 0; r < 4; ++r) {
          int v = v0 + (2 * w + rtl) * 16 + kg * 4 + r;
          if (v < 50000) {
            int colp = nt * 80 + ctl * 16 + ln;
            G[((size_t)tab * 50000 + v) * 1200 + colp] = f2bf(acc[tab][rtl][ctl][r]);
          }
        }
}

// ---------------- recurrent persistent kernel: 16 wgs x 512 thr ----------------
struct LoopSh { short x[2][16][616]; short h[2][16][328]; };
struct TailSh { float pool[16][304]; float l1[16][100]; float l2[16][5]; };
union ShU { LoopSh loop; TailSh tail; };                      // 60,416 B

template <int ONFLY>
__global__ __launch_bounds__(512, 2) void lstm_rec(
    const int* __restrict__ ids, const float* __restrict__ glove,
    const short* __restrict__ G, const short* __restrict__ Whh,
    const short* __restrict__ WihF, const float* __restrict__ biasq,
    const float* __restrict__ W1, const float* __restrict__ b1,
    const float* __restrict__ W2, const float* __restrict__ b2,
    float* __restrict__ out) {
  __shared__ ShU sh;

  const int tid = threadIdx.x;
  const int L = tid & 63, w = tid >> 6;           // 8 waves
  const int ln = L & 15, kg = L >> 4;
  const int b0 = blockIdx.x * 16;
  const int nct = (w < 4) ? 3 : 2;                // 20 col-tiles over 8 waves
  const int cts[3] = {w, w + 8, w + 16};

  int jj[3], jcl[3];
  f32x4 bq[3];
#pragma unroll
  for (int s = 0; s < 3; ++s) {
    jj[s] = cts[s] * 16 + ln;
    jcl[s] = (jj[s] < 300) ? jj[s] : 299;
    if (s < nct) bq[s] = *(const f32x4*)(biasq + 4 * jj[s]);
  }
  float creg[3][4] = {};
  float pool[3][4] = {};

  // ---- prologue: ids(t=0) + gather-issue for step 0 (g2 = 0 at t=0) ----
  const s16x4 zq = (s16x4){0, 0, 0, 0};
  int id_cur[4];
  s16x4 gq1[12], gq2[12];
#pragma unroll
  for (int r = 0; r < 4; ++r)
    id_cur[r] = ids[(size_t)(b0 + kg * 4 + r) * 512 + 0];
  if (!ONFLY) {
#pragma unroll
    for (int s = 0; s < 3; ++s) {
#pragma unroll
      for (int r = 0; r < 4; ++r) {
        gq2[s * 4 + r] = zq;
        gq1[s * 4 + r] = (s < nct)
            ? *(const s16x4*)(G + (size_t)id_cur[r] * 1200 + 4 * jcl[s]) : zq;
      }
    }
  }

  for (int i = tid; i < (int)(sizeof(LoopSh) / 2); i += 512) ((short*)&sh.loop)[i] = 0;
  __syncthreads();

  for (int t = 0; t < 512; ++t) {
    // phase 0: prefetch ids for t+1 (consumed at phase 3)
    int idn[4];
    {
      int tn = (t < 511) ? t + 1 : 511;
#pragma unroll
      for (int r = 0; r < 4; ++r)
        idn[r] = ids[(size_t)(b0 + kg * 4 + r) * 512 + tn];
    }

    if (ONFLY) {
      int r2 = tid >> 5, cl = tid & 31;
      int idt = (t < 511) ? ids[(size_t)(b0 + r2) * 512 + t] : 0;
#pragma unroll
      for (int q = 0; q < 10; ++q) {
        int c = cl + 32 * q;
        if (c < 300) {
          float v = (t < 511) ? glove[(size_t)idt * 300 + c] : 0.f;
          short bv = f2bf(v);
          sh.loop.x[t & 1][r2][c] = bv;
          sh.loop.x[(t + 1) & 1][r2][300 + c] = bv;
        }
      }
      __syncthreads();
    }

    // A fragments: h from LDS buffer (t+1)&1
    s16x8 A[10];
#pragma unroll
    for (int ks = 0; ks < 10; ++ks)
      A[ks] = *(const s16x8*)(&sh.loop.h[(t + 1) & 1][ln][ks * 32 + kg * 8]);
    s16x8 AX[ONFLY ? 19 : 1];
    if (ONFLY) {
#pragma unroll
      for (int ks = 0; ks < 19; ++ks)
        AX[ks] = *(const s16x8*)(&sh.loop.x[t & 1][ln][ks * 32 + kg * 8]);
    }

    // phase 1: B-load + MFMA (B issued before gathers -> MFMA never waits on HBM)
    f32x4 acc[3][4];
#pragma unroll
    for (int s = 0; s < 3; ++s) {
      if (s >= nct) continue;
#pragma unroll
      for (int gb = 0; gb < 4; ++gb) {
        f32x4 a = (f32x4){0.f, 0.f, 0.f, 0.f};
        const short* wb = Whh + (size_t)(cts[s] * 4 + gb) * 10 * 512;
#pragma unroll
        for (int ks = 0; ks < 10; ++ks) {
          s16x8 B = *(const s16x8*)(wb + (ks * 64 + L) * 8);
          a = mfma16(A[ks], B, a);
        }
        if (ONFLY) {
          const short* wx = WihF + (size_t)(cts[s] * 4 + gb) * 19 * 512;
#pragma unroll
          for (int ks = 0; ks < 19; ++ks) {
            s16x8 B = *(const s16x8*)(wx + (ks * 64 + L) * 8);
            a = mfma16(AX[ks], B, a);
          }
        }
        acc[s][gb] = a;
      }
    }

    // phase 3: issue G-gathers for step t+1; latency hides under the epilogue
    // (step t+1 consumes from registers with zero wait).
    s16x4 gq1n[12], gq2n[12];
    if (!ONFLY && t < 511) {
#pragma unroll
      for (int s = 0; s < 3; ++s) {
#pragma unroll
        for (int r = 0; r < 4; ++r) {
          if (s < nct) {
            // g1 for step t+1 exists iff (t+1) != 511
            gq1n[s * 4 + r] = (t < 510)
                ? *(const s16x4*)(G + (size_t)idn[r] * 1200 + 4 * jcl[s]) : zq;
            // g2 for step t+1 uses ids_t (= id_cur); (t+1) != 0 always
            gq2n[s * 4 + r] =
                *(const s16x4*)(G + ((size_t)50000 + id_cur[r]) * 1200 + 4 * jcl[s]);
          } else {
            gq1n[s * 4 + r] = zq; gq2n[s * 4 + r] = zq;
          }
        }
      }
    }

    // epilogue: register-resident gathers + bias + activations + c/h update
#pragma unroll
    for (int s = 0; s < 3; ++s) {
      if (s >= nct) continue;
      const int j = jj[s];
#pragma unroll
      for (int r = 0; r < 4; ++r) {
        float g1[4] = {0.f, 0.f, 0.f, 0.f}, g2[4] = {0.f, 0.f, 0.f, 0.f};
        if (!ONFLY) {
          s16x4 q1 = gq1[s * 4 + r], q2 = gq2[s * 4 + r];
          g1[0] = bf2f(q1.x); g1[1] = bf2f(q1.y); g1[2] = bf2f(q1.z); g1[3] = bf2f(q1.w);
          g2[0] = bf2f(q2.x); g2[1] = bf2f(q2.y); g2[2] = bf2f(q2.z); g2[3] = bf2f(q2.w);
        }
        float pi = acc[s][0][r] + g1[0] + g2[0] + bq[s].x;
        float pf = acc[s][1][r] + g1[1] + g2[1] + bq[s].y;
        float pg = acc[s][2][r] + g1[2] + g2[2] + bq[s].z;
        float po = acc[s][3][r] + g1[3] + g2[3] + bq[s].w;
        float iv = sigm(pi), fv = sigm(pf), gv = tanh_(pg), ov = sigm(po);
        float c = fv * creg[s][r] + iv * gv;
        creg[s][r] = c;
        float h = ov * tanh_(c);
        if (j >= 300) h = 0.f;
        pool[s][r] += h;
        sh.loop.h[t & 1][kg * 4 + r][j] = f2bf(h);
      }
    }

    // rotate prefetch state
#pragma unroll
    for (int r = 0; r < 4; ++r) id_cur[r] = idn[r];
    if (!ONFLY && t < 511) {
#pragma unroll
      for (int i = 0; i < 12; ++i) { gq1[i] = gq1n[i]; gq2[i] = gq2n[i]; }
    }
    __syncthreads();
  }

  // ---- tail: pooled mean -> l1 -> l2 -> log_softmax ----
#pragma unroll
  for (int s = 0; s < 3; ++s) {
    if (s >= nct) continue;
    if (jj[s] < 300) {
#pragma unroll
      for (int r = 0; r < 4; ++r)
        sh.tail.pool[kg * 4 + r][jj[s]] = pool[s][r] * (1.f / 512.f);
    }
  }
  __syncthreads();

  for (int k = 0; k < 4; ++k) {                  // 1600 dots of 300
    int it = tid + 512 * k;
    if (it < 1600) {
      int b = it & 15, o = it >> 4;
      const float* w1r = W1 + (size_t)o * 300;
      float d = b1[o];
      for (int q = 0; q < 75; ++q) {
        f32x4 pv = *(const f32x4*)(&sh.tail.pool[b][q * 4]);
        f32x4 wv = *(const f32x4*)(w1r + q * 4);
        d += pv.x * wv.x + pv.y * wv.y + pv.z * wv.z + pv.w * wv.w;
      }
      sh.tail.l1[b][o] = sigm(d);
    }
  }
  __syncthreads();
  if (tid < 80) {
    int b = tid & 15, o = tid >> 4;
    float d = b2[o];
    for (int q = 0; q < 100; ++q) d += sh.tail.l1[b][q] * W2[o * 100 + q];
    sh.tail.l2[b][o] = sigm(d);
  }
  __syncthreads();
  if (tid < 16) {
    float x0 = sh.tail.l2[tid][0], x1 = sh.tail.l2[tid][1], x2 = sh.tail.l2[tid][2],
          x3 = sh.tail.l2[tid][3], x4 = sh.tail.l2[tid][4];
    float m = fmaxf(fmaxf(fmaxf(x0, x1), fmaxf(x2, x3)), x4);
    float ssum = __expf(x0 - m) + __expf(x1 - m) + __expf(x2 - m) +
                 __expf(x3 - m) + __expf(x4 - m);
    float ls = __logf(ssum);
    float* po = out + (size_t)(b0 + tid) * 5;
    po[0] = x0 - m - ls; po[1] = x1 - m - ls; po[2] = x2 - m - ls;
    po[3] = x3 - m - ls; po[4] = x4 - m - ls;
  }
}

extern "C" void kernel_launch(void* const* d_in, const int* in_sizes, int n_in,
                              void* d_out, int out_size, void* d_ws, size_t ws_size,
                              hipStream_t stream) {
  const int*   ids   = (const int*)d_in[0];
  const float* glove = (const float*)d_in[2];
  const float* W_ih  = (const float*)d_in[3];
  const float* W_hh  = (const float*)d_in[4];
  const float* b_ih  = (const float*)d_in[5];
  const float* b_hh  = (const float*)d_in[6];
  const float* W1    = (const float*)d_in[7];
  const float* b1    = (const float*)d_in[8];
  const float* W2    = (const float*)d_in[9];
  const float* b2    = (const float*)d_in[10];
  float* out = (float*)d_out;

  char* ws = (char*)d_ws;
  short* WhhS  = (short*)(ws);                   //   819,200 B
  short* WihS  = (short*)(ws + 819200);          // 1,556,480 B
  float* biasq = (float*)(ws + 2375680);         //     5,120 B
  short* Wq    = (short*)(ws + 2380800);         // 1,536,000 B (full only)
  short* G     = (short*)(ws + 3916800);         // 240,000,000 B (full only)

  const int full = (ws_size >= (size_t)FULL_WS_BYTES) ? 1 : 0;

  prep_w<<<960, 256, 0, stream>>>(W_ih, W_hh, b_ih, b_hh, Wq, WhhS, WihS, biasq, full);
  if (full) {
    tab_gemm<<<5865, 256, 0, stream>>>(glove, Wq, G);
    lstm_rec<0><<<16, 512, 0, stream>>>(ids, glove, G, WhhS, WihS, biasq,
                                        W1, b1, W2, b2, out);
  } else {
    lstm_rec<1><<<16, 512, 0, stream>>>(ids, glove, G, WhhS, WihS, biasq,
                                        W1, b1, W2, b2, out);
  }
}

// Round 7
// 17515.993 us; speedup vs baseline: 1.0472x; 1.0391x over previous
//
#include <hip/hip_runtime.h>

// LSTM classifier, MI355X.
// emb = glove[ids];  x_t = [emb_t, emb_{t-1}]
// x @ W_ih^T == G1[ids_t] + G2[ids_{t-1}]  (G tables precomputed by tab_gemm)
// Serial part: h @ W_hh^T, batch-parallel: 16 wgs x 16 rows, h in LDS.
// R5 post-mortem: step time ~84K cycles, dominated by 120 dependent
// load->MFMA round trips of W_hh B-fragments from L2 (800KB/step/WG).
// R6 fix: double-buffered 10-fragment burst pipeline (issue burst b+1 while
// MFMA-ing burst b), h-pad 330 (bank-conflict-free), G-gathers issued after
// the B stream, consumed next step from registers.
// R7: compile fix only — ONFLY-conditional code now if constexpr (LoopF has
// no x member; runtime-if still instantiates the branch for ONFLY=0).
//
// ws layout:
//   WhhS  @ 0          819,200 B   [80 tile(ct*4+gb)][10 ks][64 L][8] bf16
//   WihS  @ 819,200  1,556,480 B   (fallback only)
//   biasq @ 2,375,680    5,120 B   [320*4] f32 quad-interleaved
//   Wq    @ 2,380,800 1,536,000 B  (full only)
//   G     @ 3,916,800 240,000,000B [2][50000][1200] bf16, col' = j*4+gate
// FULL total = 243,916,800 B; smaller ws -> on-the-fly input GEMM fallback.

typedef __attribute__((ext_vector_type(8))) short s16x8;
typedef __attribute__((ext_vector_type(4))) short s16x4;
typedef __attribute__((ext_vector_type(4))) float f32x4;

#define FULL_WS_BYTES 243916800ull

__device__ __forceinline__ float bf2f(short s) {
  unsigned u = ((unsigned)(unsigned short)s) << 16;
  float f; __builtin_memcpy(&f, &u, 4); return f;
}
__device__ __forceinline__ short f2bf(float f) {
  unsigned u; __builtin_memcpy(&u, &f, 4);
  unsigned r = u + 0x7fffu + ((u >> 16) & 1u);   // RNE
  return (short)(r >> 16);
}
__device__ __forceinline__ f32x4 mfma16(s16x8 a, s16x8 b, f32x4 c) {
  return __builtin_amdgcn_mfma_f32_16x16x32_bf16(a, b, c, 0, 0, 0);
}
__device__ __forceinline__ float sigm(float x) { return 1.f / (1.f + __expf(-x)); }
__device__ __forceinline__ float tanh_(float x) {
  float e = __expf(2.f * x);          // inf-safe
  return 1.f - 2.f / (e + 1.f);
}

// ---------------- prep: weight fragment swizzles + bias ----------------
__global__ void prep_w(const float* __restrict__ Wih, const float* __restrict__ Whh_in,
                       const float* __restrict__ bih, const float* __restrict__ bhh,
                       short* __restrict__ Wq, short* __restrict__ WhhS,
                       short* __restrict__ WihS, float* __restrict__ biasq, int full) {
  int idx = blockIdx.x * 256 + threadIdx.x;       // 960*256 = 245,760
  if (idx < 96000) {                              // Wq (full path only)
    if (!full) return;
    int tab = idx / 48000; int r = idx % 48000;
    int L = r % 64;
    int colp = (r / 640) * 16 + (L & 15);
    int rowW = (colp & 3) * 300 + (colp >> 2);    // gate*300 + j
#pragma unroll
    for (int i = 0; i < 8; ++i) {
      int k = ((r / 64) % 10) * 32 + (L >> 4) * 8 + i;
      float v = (k < 300) ? Wih[(size_t)rowW * 600 + 300 * tab + k] : 0.f;
      Wq[(size_t)idx * 8 + i] = f2bf(v);
    }
  } else if (idx < 147200) {                      // WhhS
    int r = idx - 96000;
    int tIdx = r / 640; int L = r % 64;
    int ct = tIdx >> 2, gb = tIdx & 3;
    int j = ct * 16 + (L & 15);
#pragma unroll
    for (int i = 0; i < 8; ++i) {
      int k = ((r / 64) % 10) * 32 + (L >> 4) * 8 + i;
      float v = (j < 300 && k < 300) ? Whh_in[(size_t)(gb * 300 + j) * 300 + k] : 0.f;
      WhhS[(size_t)r * 8 + i] = f2bf(v);
    }
  } else if (idx < 244480) {                      // WihS (fallback)
    int r = idx - 147200;
    int tile = r / 1216; int L = r % 64;
    int ct = tile >> 2, gb = tile & 3;
    int j = ct * 16 + (L & 15);
    int ksg = (r / 64) % 19;
#pragma unroll
    for (int i = 0; i < 8; ++i) {
      int k = ksg * 32 + (L >> 4) * 8 + i;
      float v = (j < 300 && k < 600) ? Wih[(size_t)(gb * 300 + j) * 600 + k] : 0.f;
      WihS[(size_t)r * 8 + i] = f2bf(v);
    }
  } else if (idx < 245760) {                      // biasq
    int r = idx - 244480; int j = r >> 2, gb = r & 3;
    biasq[r] = (j < 300) ? (bih[gb * 300 + j] + bhh[gb * 300 + j]) : 0.f;
  }
}

// ---------------- table GEMM: G[tab][v][col'] = glove @ W^T ----------------
__device__ __forceinline__ s16x8 loadA_gl(const float* __restrict__ g, int r, int k0) {
  s16x8 v;
  if (r < 50000) {
    if (k0 + 8 <= 300) {
      const float* p = g + (size_t)r * 300 + k0;
      f32x4 a = *(const f32x4*)p, b = *(const f32x4*)(p + 4);
      v[0] = f2bf(a.x); v[1] = f2bf(a.y); v[2] = f2bf(a.z); v[3] = f2bf(a.w);
      v[4] = f2bf(b.x); v[5] = f2bf(b.y); v[6] = f2bf(b.z); v[7] = f2bf(b.w);
    } else {
#pragma unroll
      for (int i = 0; i < 8; ++i) {
        int k = k0 + i;
        v[i] = (k < 300) ? f2bf(g[(size_t)r * 300 + k]) : (short)0;
      }
    }
  } else {
#pragma unroll
    for (int i = 0; i < 8; ++i) v[i] = 0;
  }
  return v;
}

__global__ __launch_bounds__(256, 2) void tab_gemm(const float* __restrict__ gl,
                                                   const short* __restrict__ Wq,
                                                   short* __restrict__ G) {
  int bid = blockIdx.x;                 // 391*15 blocks
  int nt = bid % 15, mt = bid / 15;
  int tid = threadIdx.x, L = tid & 63, w = tid >> 6;
  int ln = L & 15, kg = L >> 4;
  int v0 = mt * 128;

  f32x4 acc[2][2][5];
#pragma unroll
  for (int a = 0; a < 2; ++a)
#pragma unroll
    for (int b = 0; b < 2; ++b)
#pragma unroll
      for (int c = 0; c < 5; ++c) acc[a][b][c] = (f32x4){0.f, 0.f, 0.f, 0.f};

#pragma unroll
  for (int ks = 0; ks < 10; ++ks) {
    int r0 = v0 + (2 * w) * 16 + ln;
    int k0 = ks * 32 + kg * 8;
    s16x8 A0 = loadA_gl(gl, r0, k0);
    s16x8 A1 = loadA_gl(gl, r0 + 16, k0);
#pragma unroll
    for (int tab = 0; tab < 2; ++tab)
#pragma unroll
      for (int ctl = 0; ctl < 5; ++ctl) {
        const short* bp = Wq + ((((size_t)tab * 75 + nt * 5 + ctl) * 10 + ks) * 64 + L) * 8;
        s16x8 B = *(const s16x8*)bp;
        acc[tab][0][ctl] = mfma16(A0, B, acc[tab][0][ctl]);
        acc[tab][1][ctl] = mfma16(A1, B, acc[tab][1][ctl]);
      }
  }
#pragma unroll
  for (int tab = 0; tab < 2; ++tab)
#pragma unroll
    for (int rtl = 0; rtl < 2; ++rtl)
#pragma unroll
      for (int ctl = 0; ctl < 5; ++ctl)
#pragma unroll
        for (int r = 0; r < 4; ++r) {
          int v = v0 + (2 * w + rtl) * 16 + kg * 4 + r;
          if (v < 50000) {
            int colp = nt * 80 + ctl * 16 + ln;
            G[((size_t)tab * 50000 + v) * 1200 + colp] = f2bf(acc[tab][rtl][ctl][r]);
          }
        }
}

// ---------------- recurrent persistent kernel: 16 wgs x 512 thr ----------------
struct TailSh { float pool[16][304]; float l1[16][100]; float l2[16][5]; };
struct LoopF { short h[2][16][330]; };                       // 21,120 B
struct LoopO { short h[2][16][330]; short x[2][16][616]; };  // 60,544 B
template <int ONFLY> struct ShT { union { LoopO loop; TailSh tail; }; };
template <> struct ShT<0> { union { LoopF loop; TailSh tail; }; };

// Double-buffered B-fragment burst pipeline over NCT*4 bursts of 10 frags.
// All indices compile-time (full unroll) -> everything stays in VGPRs.
template <int NCT>
__device__ __forceinline__ void run_pipe(const short* __restrict__ Whh,
                                         const int* cts, int L,
                                         const s16x8* A, f32x4 (*acc)[4]) {
  s16x8 Bb0[10], Bb1[10];
  {
    const short* wb = Whh + (size_t)(cts[0] * 4 + 0) * 5120;
#pragma unroll
    for (int k = 0; k < 10; ++k) Bb0[k] = *(const s16x8*)(wb + (k * 64 + L) * 8);
  }
#pragma unroll
  for (int b = 0; b < NCT * 4; ++b) {
    const int s = b >> 2, gb = b & 3;
    if (b + 1 < NCT * 4) {                        // issue burst b+1 into other buf
      const int sn = (b + 1) >> 2, gbn = (b + 1) & 3;
      const short* wbn = Whh + (size_t)(cts[sn] * 4 + gbn) * 5120;
      if ((b & 1) == 0) {
#pragma unroll
        for (int k = 0; k < 10; ++k) Bb1[k] = *(const s16x8*)(wbn + (k * 64 + L) * 8);
      } else {
#pragma unroll
        for (int k = 0; k < 10; ++k) Bb0[k] = *(const s16x8*)(wbn + (k * 64 + L) * 8);
      }
    }
    f32x4 a = (f32x4){0.f, 0.f, 0.f, 0.f};       // consume burst b
    if ((b & 1) == 0) {
#pragma unroll
      for (int k = 0; k < 10; ++k) a = mfma16(A[k], Bb0[k], a);
    } else {
#pragma unroll
      for (int k = 0; k < 10; ++k) a = mfma16(A[k], Bb1[k], a);
    }
    acc[s][gb] = a;
  }
}

template <int ONFLY>
__global__ __launch_bounds__(512, 2) void lstm_rec(
    const int* __restrict__ ids, const float* __restrict__ glove,
    const short* __restrict__ G, const short* __restrict__ Whh,
    const short* __restrict__ WihF, const float* __restrict__ biasq,
    const float* __restrict__ W1, const float* __restrict__ b1,
    const float* __restrict__ W2, const float* __restrict__ b2,
    float* __restrict__ out) {
  __shared__ ShT<ONFLY> sh;

  const int tid = threadIdx.x;
  const int L = tid & 63, w = tid >> 6;           // 8 waves
  const int ln = L & 15, kg = L >> 4;
  const int b0 = blockIdx.x * 16;
  const int nct = (w < 4) ? 3 : 2;                // 20 col-tiles over 8 waves
  const int cts[3] = {w, w + 8, w + 16};

  int jj[3], jcl[3];
  f32x4 bq[3];
#pragma unroll
  for (int s = 0; s < 3; ++s) {
    jj[s] = cts[s] * 16 + ln;
    jcl[s] = (jj[s] < 300) ? jj[s] : 299;
    if (s < nct) bq[s] = *(const f32x4*)(biasq + 4 * jj[s]);
  }
  float creg[3][4] = {};
  float pool[3][4] = {};

  // ---- prologue: ids(t=0) + gather-issue for step 0 (g2 = 0 at t=0) ----
  const s16x4 zq = (s16x4){0, 0, 0, 0};
  int id_cur[4];
  s16x4 gq1[12], gq2[12];
#pragma unroll
  for (int r = 0; r < 4; ++r)
    id_cur[r] = ids[(size_t)(b0 + kg * 4 + r) * 512 + 0];
  if constexpr (!ONFLY) {
#pragma unroll
    for (int s = 0; s < 3; ++s) {
#pragma unroll
      for (int r = 0; r < 4; ++r) {
        gq2[s * 4 + r] = zq;
        gq1[s * 4 + r] = (s < nct)
            ? *(const s16x4*)(G + (size_t)id_cur[r] * 1200 + 4 * jcl[s]) : zq;
      }
    }
  }

  for (int i = tid; i < (int)(sizeof(sh.loop) / 2); i += 512) ((short*)&sh.loop)[i] = 0;
  __syncthreads();

  for (int t = 0; t < 512; ++t) {
    // prefetch ids for t+1 (consumed at the gather-issue phase)
    int idn[4];
    {
      int tn = (t < 511) ? t + 1 : 511;
#pragma unroll
      for (int r = 0; r < 4; ++r)
        idn[r] = ids[(size_t)(b0 + kg * 4 + r) * 512 + tn];
    }

    if constexpr (ONFLY) {
      int r2 = tid >> 5, cl = tid & 31;
      int idt = (t < 511) ? ids[(size_t)(b0 + r2) * 512 + t] : 0;
#pragma unroll
      for (int q = 0; q < 10; ++q) {
        int c = cl + 32 * q;
        if (c < 300) {
          float v = (t < 511) ? glove[(size_t)idt * 300 + c] : 0.f;
          short bv = f2bf(v);
          sh.loop.x[t & 1][r2][c] = bv;
          sh.loop.x[(t + 1) & 1][r2][300 + c] = bv;
        }
      }
      __syncthreads();
    }

    // A fragments: h from LDS buffer (t+1)&1 (row stride 330 -> conflict-free)
    s16x8 A[10];
#pragma unroll
    for (int ks = 0; ks < 10; ++ks)
      A[ks] = *(const s16x8*)(&sh.loop.h[(t + 1) & 1][ln][ks * 32 + kg * 8]);

    // B-burst pipeline (full path): latency amortized, ~10-20 loads in flight
    f32x4 acc[3][4];
    if constexpr (!ONFLY) {
      if (nct == 3) run_pipe<3>(Whh, cts, L, A, acc);
      else          run_pipe<2>(Whh, cts, L, A, acc);
    } else {
      s16x8 AX[19];
#pragma unroll
      for (int ks = 0; ks < 19; ++ks)
        AX[ks] = *(const s16x8*)(&sh.loop.x[t & 1][ln][ks * 32 + kg * 8]);
#pragma unroll
      for (int s = 0; s < 3; ++s) {
        if (s >= nct) continue;
#pragma unroll
        for (int gb = 0; gb < 4; ++gb) {
          f32x4 a = (f32x4){0.f, 0.f, 0.f, 0.f};
          const short* wb = Whh + (size_t)(cts[s] * 4 + gb) * 5120;
#pragma unroll
          for (int ks = 0; ks < 10; ++ks) {
            s16x8 B = *(const s16x8*)(wb + (ks * 64 + L) * 8);
            a = mfma16(A[ks], B, a);
          }
          const short* wx = WihF + (size_t)(cts[s] * 4 + gb) * 19 * 512;
#pragma unroll
          for (int ks = 0; ks < 19; ++ks) {
            s16x8 B = *(const s16x8*)(wx + (ks * 64 + L) * 8);
            a = mfma16(AX[ks], B, a);
          }
          acc[s][gb] = a;
        }
      }
    }

    // issue G-gathers for t+1 AFTER the B stream (younger in vmcnt order, so
    // B waits never block on them); latency hides under epilogue + next phases
    s16x4 gq1n[12], gq2n[12];
    if constexpr (!ONFLY) {
      if (t < 511) {
#pragma unroll
        for (int s = 0; s < 3; ++s) {
#pragma unroll
          for (int r = 0; r < 4; ++r) {
            if (s < nct) {
              gq1n[s * 4 + r] = (t < 510)
                  ? *(const s16x4*)(G + (size_t)idn[r] * 1200 + 4 * jcl[s]) : zq;
              gq2n[s * 4 + r] =
                  *(const s16x4*)(G + ((size_t)50000 + id_cur[r]) * 1200 + 4 * jcl[s]);
            } else {
              gq1n[s * 4 + r] = zq; gq2n[s * 4 + r] = zq;
            }
          }
        }
      }
    }

    // epilogue: register-resident gathers + bias + activations + c/h update
#pragma unroll
    for (int s = 0; s < 3; ++s) {
      if (s >= nct) continue;
      const int j = jj[s];
#pragma unroll
      for (int r = 0; r < 4; ++r) {
        float g1[4] = {0.f, 0.f, 0.f, 0.f}, g2[4] = {0.f, 0.f, 0.f, 0.f};
        if constexpr (!ONFLY) {
          s16x4 q1 = gq1[s * 4 + r], q2 = gq2[s * 4 + r];
          g1[0] = bf2f(q1.x); g1[1] = bf2f(q1.y); g1[2] = bf2f(q1.z); g1[3] = bf2f(q1.w);
          g2[0] = bf2f(q2.x); g2[1] = bf2f(q2.y); g2[2] = bf2f(q2.z); g2[3] = bf2f(q2.w);
        }
        float pi = acc[s][0][r] + g1[0] + g2[0] + bq[s].x;
        float pf = acc[s][1][r] + g1[1] + g2[1] + bq[s].y;
        float pg = acc[s][2][r] + g1[2] + g2[2] + bq[s].z;
        float po = acc[s][3][r] + g1[3] + g2[3] + bq[s].w;
        float iv = sigm(pi), fv = sigm(pf), gv = tanh_(pg), ov = sigm(po);
        float c = fv * creg[s][r] + iv * gv;
        creg[s][r] = c;
        float h = ov * tanh_(c);
        if (j >= 300) h = 0.f;
        pool[s][r] += h;
        sh.loop.h[t & 1][kg * 4 + r][j] = f2bf(h);
      }
    }

    // rotate prefetch state
#pragma unroll
    for (int r = 0; r < 4; ++r) id_cur[r] = idn[r];
    if constexpr (!ONFLY) {
      if (t < 511) {
#pragma unroll
        for (int i = 0; i < 12; ++i) { gq1[i] = gq1n[i]; gq2[i] = gq2n[i]; }
      }
    }
    __syncthreads();
  }

  // ---- tail: pooled mean -> l1 -> l2 -> log_softmax ----
#pragma unroll
  for (int s = 0; s < 3; ++s) {
    if (s >= nct) continue;
    if (jj[s] < 300) {
#pragma unroll
      for (int r = 0; r < 4; ++r)
        sh.tail.pool[kg * 4 + r][jj[s]] = pool[s][r] * (1.f / 512.f);
    }
  }
  __syncthreads();

  for (int k = 0; k < 4; ++k) {                  // 1600 dots of 300
    int it = tid + 512 * k;
    if (it < 1600) {
      int b = it & 15, o = it >> 4;
      const float* w1r = W1 + (size_t)o * 300;
      float d = b1[o];
      for (int q = 0; q < 75; ++q) {
        f32x4 pv = *(const f32x4*)(&sh.tail.pool[b][q * 4]);
        f32x4 wv = *(const f32x4*)(w1r + q * 4);
        d += pv.x * wv.x + pv.y * wv.y + pv.z * wv.z + pv.w * wv.w;
      }
      sh.tail.l1[b][o] = sigm(d);
    }
  }
  __syncthreads();
  if (tid < 80) {
    int b = tid & 15, o = tid >> 4;
    float d = b2[o];
    for (int q = 0; q < 100; ++q) d += sh.tail.l1[b][q] * W2[o * 100 + q];
    sh.tail.l2[b][o] = sigm(d);
  }
  __syncthreads();
  if (tid < 16) {
    float x0 = sh.tail.l2[tid][0], x1 = sh.tail.l2[tid][1], x2 = sh.tail.l2[tid][2],
          x3 = sh.tail.l2[tid][3], x4 = sh.tail.l2[tid][4];
    float m = fmaxf(fmaxf(fmaxf(x0, x1), fmaxf(x2, x3)), x4);
    float ssum = __expf(x0 - m) + __expf(x1 - m) + __expf(x2 - m) +
                 __expf(x3 - m) + __expf(x4 - m);
    float ls = __logf(ssum);
    float* po = out + (size_t)(b0 + tid) * 5;
    po[0] = x0 - m - ls; po[1] = x1 - m - ls; po[2] = x2 - m - ls;
    po[3] = x3 - m - ls; po[4] = x4 - m - ls;
  }
}

extern "C" void kernel_launch(void* const* d_in, const int* in_sizes, int n_in,
                              void* d_out, int out_size, void* d_ws, size_t ws_size,
                              hipStream_t stream) {
  const int*   ids   = (const int*)d_in[0];
  const float* glove = (const float*)d_in[2];
  const float* W_ih  = (const float*)d_in[3];
  const float* W_hh  = (const float*)d_in[4];
  const float* b_ih  = (const float*)d_in[5];
  const float* b_hh  = (const float*)d_in[6];
  const float* W1    = (const float*)d_in[7];
  const float* b1    = (const float*)d_in[8];
  const float* W2    = (const float*)d_in[9];
  const float* b2    = (const float*)d_in[10];
  float* out = (float*)d_out;

  char* ws = (char*)d_ws;
  short* WhhS  = (short*)(ws);                   //   819,200 B
  short* WihS  = (short*)(ws + 819200);          // 1,556,480 B
  float* biasq = (float*)(ws + 2375680);         //     5,120 B
  short* Wq    = (short*)(ws + 2380800);         // 1,536,000 B (full only)
  short* G     = (short*)(ws + 3916800);         // 240,000,000 B (full only)

  const int full = (ws_size >= (size_t)FULL_WS_BYTES) ? 1 : 0;

  prep_w<<<960, 256, 0, stream>>>(W_ih, W_hh, b_ih, b_hh, Wq, WhhS, WihS, biasq, full);
  if (full) {
    tab_gemm<<<5865, 256, 0, stream>>>(glove, Wq, G);
    lstm_rec<0><<<16, 512, 0, stream>>>(ids, glove, G, WhhS, WihS, biasq,
                                        W1, b1, W2, b2, out);
  } else {
    lstm_rec<1><<<16, 512, 0, stream>>>(ids, glove, G, WhhS, WihS, biasq,
                                        W1, b1, W2, b2, out);
  }
}